// Round 2
// baseline (536.034 us; speedup 1.0000x reference)
//
#include <hip/hip_runtime.h>
#include <hip/hip_bf16.h>

typedef __attribute__((ext_vector_type(4))) float f32x4;
typedef __attribute__((ext_vector_type(8))) short short8;
typedef __attribute__((ext_vector_type(8))) __bf16 bf16x8;

#define NDIM 172
#define EDIM 172
#define TDIM 100
#define KCAT 444   // 172+172+100
#define KPAD 448
#define QDIM 272   // 172+100
#define ODIM 128
#define ZDIM 256
#define NNBR 32
#define BPB 4      // batch rows per fused block
#define KSTEP 64
#define LN_EPS 1e-5f

// Z_lds byte offset with XOR bank-swizzle (row stride 512 B)
#define ZB(r,c) ((((r) * 512) + ((c) * 2)) ^ (((r) & 7) << 4))

__device__ __forceinline__ unsigned short f2bf(float f) {
    unsigned u = __builtin_bit_cast(unsigned, f);
    u += 0x7fffu + ((u >> 16) & 1u);
    return (unsigned short)(u >> 16);
}
__device__ __forceinline__ float bf2f(unsigned short h) {
    unsigned u = ((unsigned)h) << 16;
    return __builtin_bit_cast(float, u);
}

// ---- prep: pack Wkv [256][444]->bf16[256][448], WqT bf16[272][128], WoT bf16[128][128]
#define WKV_N (256 * KPAD)          // 114688
#define WQT_N (QDIM * ODIM)         // 34816
#define WOT_N (ODIM * ODIM)         // 16384
__global__ void prep_pack(const float* __restrict__ Wkv, const float* __restrict__ Wq,
                          const float* __restrict__ Wo,
                          unsigned short* __restrict__ wpack,
                          unsigned short* __restrict__ wqT,
                          unsigned short* __restrict__ woT) {
    int idx = blockIdx.x * 256 + threadIdx.x;
    if (idx < WKV_N) {
        int row = idx / KPAD, k = idx - row * KPAD;
        wpack[idx] = f2bf((k < KCAT) ? Wkv[row * KCAT + k] : 0.f);
    } else if (idx < WKV_N + WQT_N) {
        int j = idx - WKV_N;
        int k = j >> 7, c = j & 127;
        wqT[j] = f2bf(Wq[c * QDIM + k]);
    } else if (idx < WKV_N + WQT_N + WOT_N) {
        int j = idx - WKV_N - WQT_N;
        int k = j >> 7, c = j & 127;
        woT[j] = f2bf(Wo[c * ODIM + k]);
    }
}

// ---- Q projection: Q[B,128] = concat(node,time) @ Wq^T + bq  (coalesced via WqT)
__global__ __launch_bounds__(256) void q_proj(
    const float* __restrict__ node_feat, const float* __restrict__ time_feat,
    const unsigned short* __restrict__ wqT, const float* __restrict__ bq,
    float* __restrict__ Qbuf) {
    __shared__ float x[8][QDIM];
    const int tid = threadIdx.x;
    const long b0 = (long)blockIdx.x * 8;
    for (int g = tid; g < 8 * QDIM; g += 256) {
        int r = g / QDIM, k = g - r * QDIM;
        x[r][k] = (k < NDIM) ? node_feat[(b0 + r) * NDIM + k]
                             : time_feat[(b0 + r) * TDIM + (k - NDIM)];
    }
    __syncthreads();
    const int c = tid & 127;
    const int rb = (tid >> 7) * 4;
    float s0 = bq[c], s1 = s0, s2 = s0, s3 = s0;
    #pragma unroll 8
    for (int k = 0; k < QDIM; k++) {
        float w = bf2f(wqT[k * 128 + c]);
        s0 += x[rb + 0][k] * w;
        s1 += x[rb + 1][k] * w;
        s2 += x[rb + 2][k] * w;
        s3 += x[rb + 3][k] * w;
    }
    Qbuf[(b0 + rb + 0) * 128 + c] = s0;
    Qbuf[(b0 + rb + 1) * 128 + c] = s1;
    Qbuf[(b0 + rb + 2) * 128 + c] = s2;
    Qbuf[(b0 + rb + 3) * 128 + c] = s3;
}

__global__ __launch_bounds__(512, 4) void ta_fused(
    const float* __restrict__ edge_feat, const float* __restrict__ nbr_node,
    const float* __restrict__ nbr_time, const int* __restrict__ nbr_mask,
    const float* __restrict__ Qbuf,
    const unsigned short* __restrict__ wpack, const float* __restrict__ bkv,
    const unsigned short* __restrict__ woT, const float* __restrict__ bo,
    const float* __restrict__ gamma, const float* __restrict__ beta,
    float* __restrict__ out)
{
    // union: GEMM staging (A bf16 [128][64] @0 = 16K, W bf16 [256][64] @16K = 32K)
    // then Z bf16 [128][256] swizzled (64K)
    __shared__ __align__(16) unsigned char smem[65536];
    __shared__ float qres[BPB][ODIM];
    __shared__ float Pband[BPB][2][NNBR];
    __shared__ float Obuf[BPB][ODIM];
    __shared__ float red[8][2];

    const int tid  = threadIdx.x;
    const int lane = tid & 63;
    const int wid  = tid >> 6;
    const int b0   = blockIdx.x * BPB;

    // ---- stage precomputed Q rows (coalesced, 512 floats)
    {
        int b = tid >> 7, c = tid & 127;
        qres[b][c] = Qbuf[(long)(b0 + b) * ODIM + c];
    }

    // ---- GEMM: Z[128][256] = A[128][448] * Wkv_packed[256][448]^T
    f32x4 acc[4][4];
    #pragma unroll
    for (int m = 0; m < 4; m++)
        #pragma unroll
        for (int n = 0; n < 4; n++) acc[m][n] = (f32x4){0.f, 0.f, 0.f, 0.f};

    const int wm = wid >> 2;   // 0..1 : 64-row band
    const int wn = wid & 3;    // 0..3 : 64-col band

    // per-thread constant staging geometry
    float4 areg[4];
    uint4  wreg[4];
    int a_row[4], a_grp[4];
    int w_row[4], w_f8[4];
    #pragma unroll
    for (int i = 0; i < 4; i++) {
        int g = i * 512 + tid;
        a_row[i] = g >> 4; a_grp[i] = g & 15;
        w_row[i] = g >> 3; w_f8[i]  = g & 7;
    }

    auto ISSUE = [&](int k0) {
        #pragma unroll
        for (int i = 0; i < 4; i++) {
            int k = k0 + a_grp[i] * 4;
            int bl = a_row[i] >> 5, n = a_row[i] & 31;
            long rg = (long)(b0 + bl) * NNBR + n;
            float4 v;
            if (k < NDIM)             v = *(const float4*)(nbr_node  + rg * NDIM + k);
            else if (k < NDIM + EDIM) v = *(const float4*)(edge_feat + rg * EDIM + (k - NDIM));
            else if (k < KCAT)        v = *(const float4*)(nbr_time  + rg * TDIM + (k - NDIM - EDIM));
            else                      v = make_float4(0.f, 0.f, 0.f, 0.f);
            areg[i] = v;
        }
        #pragma unroll
        for (int i = 0; i < 4; i++)
            wreg[i] = *(const uint4*)(wpack + (long)w_row[i] * KPAD + k0 + w_f8[i] * 8);
    };

    ISSUE(0);

    for (int ks = 0; ks < KPAD / KSTEP; ks++) {
        // write staged regs -> LDS (compiler inserts the vmcnt waits)
        #pragma unroll
        for (int i = 0; i < 4; i++) {
            ushort4 h = make_ushort4(f2bf(areg[i].x), f2bf(areg[i].y),
                                     f2bf(areg[i].z), f2bf(areg[i].w));
            int byte = (a_row[i] * 128 + a_grp[i] * 8) ^ ((a_row[i] & 7) << 4);
            *(ushort4*)(smem + byte) = h;
        }
        #pragma unroll
        for (int i = 0; i < 4; i++) {
            int byte = (w_row[i] * 128 + w_f8[i] * 16) ^ ((w_row[i] & 7) << 4);
            *(uint4*)(smem + 16384 + byte) = wreg[i];
        }
        __syncthreads();
        if (ks < KPAD / KSTEP - 1) ISSUE((ks + 1) * KSTEP);  // prefetch under compute
        // compute: two K=32 halves
        #pragma unroll
        for (int kk = 0; kk < 2; kk++) {
            const int kb = kk * 64 + (lane >> 4) * 16;
            bf16x8 af[4], bfr[4];
            #pragma unroll
            for (int m = 0; m < 4; m++) {
                int row = wm * 64 + m * 16 + (lane & 15);
                int byte = (row * 128 + kb) ^ ((row & 7) << 4);
                af[m] = __builtin_bit_cast(bf16x8, *(const short8*)(smem + byte));
            }
            #pragma unroll
            for (int n = 0; n < 4; n++) {
                int row = wn * 64 + n * 16 + (lane & 15);
                int byte = (row * 128 + kb) ^ ((row & 7) << 4);
                bfr[n] = __builtin_bit_cast(bf16x8, *(const short8*)(smem + 16384 + byte));
            }
            #pragma unroll
            for (int m = 0; m < 4; m++)
                #pragma unroll
                for (int n = 0; n < 4; n++)
                    acc[m][n] = __builtin_amdgcn_mfma_f32_16x16x32_bf16(af[m], bfr[n], acc[m][n], 0, 0, 0);
        }
        __syncthreads();
    }

    // ---- dump Z (+bkv) to LDS as bf16 (swizzled); C/D: col=lane&15, row=(lane>>4)*4+j
    #pragma unroll
    for (int n = 0; n < 4; n++) {
        int col = wn * 64 + n * 16 + (lane & 15);
        float bk = bkv[col];
        #pragma unroll
        for (int m = 0; m < 4; m++) {
            #pragma unroll
            for (int j = 0; j < 4; j++) {
                int row = wm * 64 + m * 16 + (lane >> 4) * 4 + j;
                *(unsigned short*)(smem + ZB(row, col)) = f2bf(acc[m][n][j] + bk);
            }
        }
    }
    __syncthreads();

    // ---- scores + softmax: wave w -> (b=w>>1, h=w&1); lane pair per position n2
    {
        int bl = wid >> 1, h = wid & 1;
        int n2 = lane >> 1, half = lane & 1;
        int np = h * 16 + (n2 >> 1);                  // Z row (mixed reshape)
        int rowZ = bl * NNBR + np;
        int cb = (n2 & 1) * 64 + half * 32;           // Z col base (K part)
        const float* q = &qres[bl][h * 64 + half * 32];
        float s = 0.f;
        #pragma unroll 8
        for (int d = 0; d < 32; d++)
            s += q[d] * bf2f(*(const unsigned short*)(smem + ZB(rowZ, cb + d)));
        s += __shfl_xor(s, 1);
        s *= 0.125f;  // HEAD_DIM^-0.5
        if (nbr_mask[(long)(b0 + bl) * NNBR + n2] == 0) s = -1e10f;
        float mx = s;
        #pragma unroll
        for (int off = 1; off < 64; off <<= 1) mx = fmaxf(mx, __shfl_xor(mx, off));
        float e = __expf(s - mx);
        float sum = e;
        #pragma unroll
        for (int off = 1; off < 64; off <<= 1) sum += __shfl_xor(sum, off);
        float p = e * 2.f / sum;   // each n2 counted twice in sum
        if (half == 0) Pband[bl][h][n2] = p;
    }
    __syncthreads();

    // ---- O = P @ V : one thread per (b, h*64+d)
    {
        int b = tid >> 7, c = tid & 127, h = c >> 6, d = c & 63;
        const float* P = Pband[b][h];
        float s = 0.f;
        #pragma unroll
        for (int n2 = 0; n2 < NNBR; n2++) {
            int np = h * 16 + (n2 >> 1);
            int col = ODIM + (n2 & 1) * 64 + d;       // V part
            s += P[n2] * bf2f(*(const unsigned short*)(smem + ZB(b * NNBR + np, col)));
        }
        Obuf[b][c] = s;
    }
    __syncthreads();

    // ---- out proj (coalesced via WoT) + LayerNorm
    {
        int b = tid >> 7, c = tid & 127;
        float s = bo[c];
        const float* ob = Obuf[b];
        #pragma unroll 8
        for (int k = 0; k < ODIM; k++)
            s += ob[k] * bf2f(woT[k * 128 + c]);
        float s1 = s, s2 = s * s;
        #pragma unroll
        for (int off = 1; off < 64; off <<= 1) {
            s1 += __shfl_xor(s1, off);
            s2 += __shfl_xor(s2, off);
        }
        if (lane == 0) { red[wid][0] = s1; red[wid][1] = s2; }
        __syncthreads();
        float t1 = red[b * 2][0] + red[b * 2 + 1][0];
        float t2 = red[b * 2][1] + red[b * 2 + 1][1];
        float mu  = t1 * (1.f / 128.f);
        float var = t2 * (1.f / 128.f) - mu * mu;
        float inv = rsqrtf(var + LN_EPS);
        out[(long)(b0 + b) * ODIM + c] = (s - mu) * inv * gamma[c] + beta[c];
    }
}

extern "C" void kernel_launch(void* const* d_in, const int* in_sizes, int n_in,
                              void* d_out, int out_size, void* d_ws, size_t ws_size,
                              hipStream_t stream) {
    const float* node_feat = (const float*)d_in[0];
    const float* time_feat = (const float*)d_in[1];
    const float* edge_feat = (const float*)d_in[2];
    const float* nbr_node  = (const float*)d_in[3];
    const float* nbr_time  = (const float*)d_in[4];
    const int*   nbr_mask  = (const int*)d_in[5];
    const float* Wq   = (const float*)d_in[6];
    const float* bq   = (const float*)d_in[7];
    const float* Wkv  = (const float*)d_in[8];
    const float* bkv  = (const float*)d_in[9];
    const float* Wo   = (const float*)d_in[10];
    const float* bo   = (const float*)d_in[11];
    const float* gma  = (const float*)d_in[12];
    const float* bta  = (const float*)d_in[13];
    float* out = (float*)d_out;

    const int B = in_sizes[0] / NDIM;  // 8192

    // workspace layout
    char* ws = (char*)d_ws;
    float* Qbuf = (float*)ws;                                   // B*128*4 = 4 MB
    unsigned short* wpack = (unsigned short*)(ws + (size_t)B * ODIM * 4);
    unsigned short* wqT   = wpack + WKV_N;
    unsigned short* woT   = wqT + WQT_N;

    const int prep_total = WKV_N + WQT_N + WOT_N;
    prep_pack<<<dim3((prep_total + 255) / 256), dim3(256), 0, stream>>>(
        Wkv, Wq, Wo, wpack, wqT, woT);
    q_proj<<<dim3(B / 8), dim3(256), 0, stream>>>(node_feat, time_feat, wqT, bq, Qbuf);
    ta_fused<<<dim3(B / BPB), dim3(512), 0, stream>>>(
        edge_feat, nbr_node, nbr_time, nbr_mask, Qbuf,
        wpack, bkv, woT, bo, gma, bta, out);
}

// Round 3
// 218.952 us; speedup vs baseline: 2.4482x; 2.4482x over previous
//
#include <hip/hip_runtime.h>
#include <hip/hip_bf16.h>

typedef __attribute__((ext_vector_type(4))) float f32x4;
typedef __attribute__((ext_vector_type(8))) short short8;
typedef __attribute__((ext_vector_type(8))) __bf16 bf16x8;

#define NDIM 172
#define EDIM 172
#define TDIM 100
#define KCAT 444   // 172+172+100
#define KPAD 448
#define QDIM 272   // 172+100
#define ODIM 128
#define ZDIM 256
#define NNBR 32
#define BPB 4      // batch rows per fused block
#define KSTEP 64
#define NKS (KPAD / KSTEP)   // 7
#define LN_EPS 1e-5f

// Z_lds byte offset with XOR bank-swizzle (row stride 512 B)
#define ZB(r,c) ((((r) * 512) + ((c) * 2)) ^ (((r) & 7) << 4))

__device__ __forceinline__ unsigned short f2bf(float f) {
    unsigned u = __builtin_bit_cast(unsigned, f);
    u += 0x7fffu + ((u >> 16) & 1u);
    return (unsigned short)(u >> 16);
}
__device__ __forceinline__ float bf2f(unsigned short h) {
    unsigned u = ((unsigned)h) << 16;
    return __builtin_bit_cast(float, u);
}

// async global->LDS, 16 bytes per lane (lane-contiguous dest)
__device__ __forceinline__ void gll16(const void* g, void* l) {
    __builtin_amdgcn_global_load_lds(
        (const __attribute__((address_space(1))) unsigned int*)g,
        (__attribute__((address_space(3))) unsigned int*)l,
        16, 0, 0);
}

// ---- prep: wswz = Wkv bf16, pre-permuted per 64-K tile so that a LINEAR
// global_load_lds produces the XOR-swizzled LDS layout the MFMA reads use.
// Also WqT bf16[272][128], WoT bf16[128][128].
#define WKV_N (256 * KPAD)          // 114688 shorts (7 tiles x 16384)
#define WQT_N (QDIM * ODIM)         // 34816
#define WOT_N (ODIM * ODIM)         // 16384
__global__ void prep_pack(const float* __restrict__ Wkv, const float* __restrict__ Wq,
                          const float* __restrict__ Wo,
                          unsigned short* __restrict__ wswz,
                          unsigned short* __restrict__ wqT,
                          unsigned short* __restrict__ woT) {
    int idx = blockIdx.x * 256 + threadIdx.x;
    if (idx < WKV_N) {
        int tile = idx >> 14;            // 16384 shorts per K-tile
        int qb   = (idx & 16383) * 2;    // byte offset within tile's LDS image
        int row  = qb >> 7;              // W row (128 B per row)
        int x    = qb & 127;
        int f8   = (x ^ ((row & 7) << 4)) >> 4;   // inverse of the read swizzle
        int e    = (x & 15) >> 1;
        int k    = tile * KSTEP + f8 * 8 + e;
        wswz[idx] = f2bf((k < KCAT) ? Wkv[row * KCAT + k] : 0.f);
    } else if (idx < WKV_N + WQT_N) {
        int j = idx - WKV_N;
        int k = j >> 7, c = j & 127;
        wqT[j] = f2bf(Wq[c * QDIM + k]);
    } else if (idx < WKV_N + WQT_N + WOT_N) {
        int j = idx - WKV_N - WQT_N;
        int k = j >> 7, c = j & 127;
        woT[j] = f2bf(Wo[c * ODIM + k]);
    }
}

// ---- Q projection: Q[B,128] = concat(node,time) @ Wq^T + bq  (coalesced via WqT)
__global__ __launch_bounds__(256) void q_proj(
    const float* __restrict__ node_feat, const float* __restrict__ time_feat,
    const unsigned short* __restrict__ wqT, const float* __restrict__ bq,
    float* __restrict__ Qbuf) {
    __shared__ float x[8][QDIM];
    const int tid = threadIdx.x;
    const long b0 = (long)blockIdx.x * 8;
    for (int g = tid; g < 8 * QDIM; g += 256) {
        int r = g / QDIM, k = g - r * QDIM;
        x[r][k] = (k < NDIM) ? node_feat[(b0 + r) * NDIM + k]
                             : time_feat[(b0 + r) * TDIM + (k - NDIM)];
    }
    __syncthreads();
    const int c = tid & 127;
    const int rb = (tid >> 7) * 4;
    float s0 = bq[c], s1 = s0, s2 = s0, s3 = s0;
    #pragma unroll 8
    for (int k = 0; k < QDIM; k++) {
        float w = bf2f(wqT[k * 128 + c]);
        s0 += x[rb + 0][k] * w;
        s1 += x[rb + 1][k] * w;
        s2 += x[rb + 2][k] * w;
        s3 += x[rb + 3][k] * w;
    }
    Qbuf[(b0 + rb + 0) * 128 + c] = s0;
    Qbuf[(b0 + rb + 1) * 128 + c] = s1;
    Qbuf[(b0 + rb + 2) * 128 + c] = s2;
    Qbuf[(b0 + rb + 3) * 128 + c] = s3;
}

__global__ __launch_bounds__(512) void ta_fused(
    const float* __restrict__ edge_feat, const float* __restrict__ nbr_node,
    const float* __restrict__ nbr_time, const int* __restrict__ nbr_mask,
    const float* __restrict__ Qbuf,
    const unsigned short* __restrict__ wswz, const float* __restrict__ bkv,
    const unsigned short* __restrict__ woT, const float* __restrict__ bo,
    const float* __restrict__ gamma, const float* __restrict__ beta,
    float* __restrict__ out)
{
    // union: GEMM staging (A bf16 swz [128][64] @0 = 16K, W swz [256][64] @16K = 32K)
    // then Z bf16 [128][256] swizzled (64K)
    __shared__ __align__(16) unsigned char smem[65536];
    __shared__ float qres[BPB][ODIM];
    __shared__ float Pband[BPB][2][NNBR];
    __shared__ float Obuf[BPB][ODIM];
    __shared__ float red[8][2];

    const int tid  = threadIdx.x;
    const int lane = tid & 63;
    const int wid  = tid >> 6;
    const int b0   = blockIdx.x * BPB;

    // ---- stage precomputed Q rows (coalesced, 512 floats)
    {
        int b = tid >> 7, c = tid & 127;
        qres[b][c] = Qbuf[(long)(b0 + b) * ODIM + c];
    }

    // ---- GEMM: Z[128][256] = A[128][448] * Wkv[256][448]^T
    f32x4 acc[4][4];
    #pragma unroll
    for (int m = 0; m < 4; m++)
        #pragma unroll
        for (int n = 0; n < 4; n++) acc[m][n] = (f32x4){0.f, 0.f, 0.f, 0.f};

    const int wm = wid >> 2;   // 0..1 : 64-row band
    const int wn = wid & 3;    // 0..3 : 64-col band

    // per-thread constant staging geometry (hoisted out of the K loop)
    float4 areg[4];
    const float* pN[4]; const float* pE[4]; const float* pT[4];
    int a_koff[4], a_byte[4];
    #pragma unroll
    for (int i = 0; i < 4; i++) {
        int g = i * 512 + tid;
        int row = g >> 4, grp = g & 15;
        int bl = row >> 5, n = row & 31;
        long rg = (long)(b0 + bl) * NNBR + n;
        pN[i] = nbr_node  + rg * NDIM;
        pE[i] = edge_feat + rg * EDIM;
        pT[i] = nbr_time  + rg * TDIM;
        a_koff[i] = grp * 4;
        a_byte[i] = (row * 128 + grp * 8) ^ ((row & 7) << 4);
    }

    auto ISSUE_A = [&](int k0) {
        #pragma unroll
        for (int i = 0; i < 4; i++) {
            int k = k0 + a_koff[i];
            float4 v;
            if (k < NDIM)             v = *(const float4*)(pN[i] + k);
            else if (k < NDIM + EDIM) v = *(const float4*)(pE[i] + (k - NDIM));
            else if (k < KCAT)        v = *(const float4*)(pT[i] + (k - NDIM - EDIM));
            else                      v = make_float4(0.f, 0.f, 0.f, 0.f);
            areg[i] = v;
        }
    };

    ISSUE_A(0);

    for (int ks = 0; ks < NKS; ks++) {
        // W tile: pre-swizzled source, linear lane-contiguous async copy to LDS
        #pragma unroll
        for (int j = 0; j < 4; j++) {
            int s = j * 512 + tid;   // 16B chunk index [0,2048)
            gll16(wswz + (size_t)ks * 16384 + s * 8, smem + 16384 + s * 16);
        }
        // A tile: staged regs -> bf16 -> swizzled LDS
        #pragma unroll
        for (int i = 0; i < 4; i++) {
            ushort4 h = make_ushort4(f2bf(areg[i].x), f2bf(areg[i].y),
                                     f2bf(areg[i].z), f2bf(areg[i].w));
            *(ushort4*)(smem + a_byte[i]) = h;
        }
        __syncthreads();                       // drains vmcnt (GLL) + lgkm
        if (ks < NKS - 1) ISSUE_A((ks + 1) * KSTEP);  // prefetch under compute
        // compute: two K=32 halves
        #pragma unroll
        for (int kk = 0; kk < 2; kk++) {
            const int kb = kk * 64 + (lane >> 4) * 16;
            bf16x8 af[4], bfr[4];
            #pragma unroll
            for (int m = 0; m < 4; m++) {
                int row = wm * 64 + m * 16 + (lane & 15);
                int byte = (row * 128 + kb) ^ ((row & 7) << 4);
                af[m] = __builtin_bit_cast(bf16x8, *(const short8*)(smem + byte));
            }
            #pragma unroll
            for (int n = 0; n < 4; n++) {
                int row = wn * 64 + n * 16 + (lane & 15);
                int byte = (row * 128 + kb) ^ ((row & 7) << 4);
                bfr[n] = __builtin_bit_cast(bf16x8, *(const short8*)(smem + 16384 + byte));
            }
            #pragma unroll
            for (int m = 0; m < 4; m++)
                #pragma unroll
                for (int n = 0; n < 4; n++)
                    acc[m][n] = __builtin_amdgcn_mfma_f32_16x16x32_bf16(af[m], bfr[n], acc[m][n], 0, 0, 0);
        }
        __syncthreads();
    }

    // ---- dump Z (+bkv) to LDS as bf16 (swizzled); C/D: col=lane&15, row=(lane>>4)*4+j
    #pragma unroll
    for (int n = 0; n < 4; n++) {
        int col = wn * 64 + n * 16 + (lane & 15);
        float bk = bkv[col];
        #pragma unroll
        for (int m = 0; m < 4; m++) {
            #pragma unroll
            for (int j = 0; j < 4; j++) {
                int row = wm * 64 + m * 16 + (lane >> 4) * 4 + j;
                *(unsigned short*)(smem + ZB(row, col)) = f2bf(acc[m][n][j] + bk);
            }
        }
    }
    __syncthreads();

    // ---- scores + softmax: wave w -> (b=w>>1, h=w&1); lane pair per position n2
    {
        int bl = wid >> 1, h = wid & 1;
        int n2 = lane >> 1, half = lane & 1;
        int np = h * 16 + (n2 >> 1);                  // Z row (mixed reshape)
        int rowZ = bl * NNBR + np;
        int cb = (n2 & 1) * 64 + half * 32;           // Z col base (K part)
        const float* q = &qres[bl][h * 64 + half * 32];
        float s = 0.f;
        #pragma unroll
        for (int j = 0; j < 4; j++) {
            short8 z8 = *(const short8*)(smem + ZB(rowZ, cb + j * 8));
            #pragma unroll
            for (int e = 0; e < 8; e++)
                s += q[j * 8 + e] * bf2f((unsigned short)z8[e]);
        }
        s += __shfl_xor(s, 1);
        s *= 0.125f;  // HEAD_DIM^-0.5
        if (nbr_mask[(long)(b0 + bl) * NNBR + n2] == 0) s = -1e10f;
        float mx = s;
        #pragma unroll
        for (int off = 1; off < 64; off <<= 1) mx = fmaxf(mx, __shfl_xor(mx, off));
        float e = __expf(s - mx);
        float sum = e;
        #pragma unroll
        for (int off = 1; off < 64; off <<= 1) sum += __shfl_xor(sum, off);
        float p = e * 2.f / sum;   // each n2 counted twice in sum
        if (half == 0) Pband[bl][h][n2] = p;
    }
    __syncthreads();

    // ---- O = P @ V : one thread per (b, h*64+d)
    {
        int b = tid >> 7, c = tid & 127, h = c >> 6, d = c & 63;
        const float* P = Pband[b][h];
        float s = 0.f;
        #pragma unroll
        for (int n2 = 0; n2 < NNBR; n2++) {
            int np = h * 16 + (n2 >> 1);
            int col = ODIM + (n2 & 1) * 64 + d;       // V part
            s += P[n2] * bf2f(*(const unsigned short*)(smem + ZB(b * NNBR + np, col)));
        }
        Obuf[b][c] = s;
    }
    __syncthreads();

    // ---- out proj (coalesced via WoT) + LayerNorm
    {
        int b = tid >> 7, c = tid & 127;
        float s = bo[c];
        const float* ob = Obuf[b];
        #pragma unroll 8
        for (int k = 0; k < ODIM; k++)
            s += ob[k] * bf2f(woT[k * 128 + c]);
        float s1 = s, s2 = s * s;
        #pragma unroll
        for (int off = 1; off < 64; off <<= 1) {
            s1 += __shfl_xor(s1, off);
            s2 += __shfl_xor(s2, off);
        }
        if (lane == 0) { red[wid][0] = s1; red[wid][1] = s2; }
        __syncthreads();
        float t1 = red[b * 2][0] + red[b * 2 + 1][0];
        float t2 = red[b * 2][1] + red[b * 2 + 1][1];
        float mu  = t1 * (1.f / 128.f);
        float var = t2 * (1.f / 128.f) - mu * mu;
        float inv = rsqrtf(var + LN_EPS);
        out[(long)(b0 + b) * ODIM + c] = (s - mu) * inv * gamma[c] + beta[c];
    }
}

extern "C" void kernel_launch(void* const* d_in, const int* in_sizes, int n_in,
                              void* d_out, int out_size, void* d_ws, size_t ws_size,
                              hipStream_t stream) {
    const float* node_feat = (const float*)d_in[0];
    const float* time_feat = (const float*)d_in[1];
    const float* edge_feat = (const float*)d_in[2];
    const float* nbr_node  = (const float*)d_in[3];
    const float* nbr_time  = (const float*)d_in[4];
    const int*   nbr_mask  = (const int*)d_in[5];
    const float* Wq   = (const float*)d_in[6];
    const float* bq   = (const float*)d_in[7];
    const float* Wkv  = (const float*)d_in[8];
    const float* bkv  = (const float*)d_in[9];
    const float* Wo   = (const float*)d_in[10];
    const float* bo   = (const float*)d_in[11];
    const float* gma  = (const float*)d_in[12];
    const float* bta  = (const float*)d_in[13];
    float* out = (float*)d_out;

    const int B = in_sizes[0] / NDIM;  // 8192

    // workspace layout
    char* ws = (char*)d_ws;
    float* Qbuf = (float*)ws;                                   // B*128*4 = 4 MB
    unsigned short* wswz = (unsigned short*)(ws + (size_t)B * ODIM * 4);
    unsigned short* wqT  = wswz + WKV_N;
    unsigned short* woT  = wqT + WQT_N;

    const int prep_total = WKV_N + WQT_N + WOT_N;
    prep_pack<<<dim3((prep_total + 255) / 256), dim3(256), 0, stream>>>(
        Wkv, Wq, Wo, wswz, wqT, woT);
    q_proj<<<dim3(B / 8), dim3(256), 0, stream>>>(node_feat, time_feat, wqT, bq, Qbuf);
    ta_fused<<<dim3(B / BPB), dim3(512), 0, stream>>>(
        edge_feat, nbr_node, nbr_time, nbr_mask, Qbuf,
        wswz, bkv, woT, bo, gma, bta, out);
}

// Round 4
// 200.075 us; speedup vs baseline: 2.6792x; 1.0944x over previous
//
#include <hip/hip_runtime.h>
#include <hip/hip_bf16.h>

typedef __attribute__((ext_vector_type(4))) float f32x4;
typedef __attribute__((ext_vector_type(8))) short short8;
typedef __attribute__((ext_vector_type(8))) __bf16 bf16x8;

#define NDIM 172
#define EDIM 172
#define TDIM 100
#define KCAT 444   // 172+172+100
#define KPAD 448
#define QDIM 272   // 172+100
#define ODIM 128
#define ZDIM 256
#define NNBR 32
#define BPB 2      // batch rows per fused block (M = 64)
#define MROWS (BPB * NNBR)
#define KSTEP 64
#define NKS (KPAD / KSTEP)   // 7
#define LN_EPS 1e-5f

// Z_lds byte offset with XOR bank-swizzle (row stride 512 B)
#define ZB(r,c) ((((r) * 512) + ((c) * 2)) ^ (((r) & 7) << 4))

#define W_LDS_OFF 8192   // A staging: [64][64] bf16 swz = 8 KB; W: [256][64] = 32 KB

__device__ __forceinline__ unsigned short f2bf(float f) {
    unsigned u = __builtin_bit_cast(unsigned, f);
    u += 0x7fffu + ((u >> 16) & 1u);
    return (unsigned short)(u >> 16);
}
__device__ __forceinline__ float bf2f(unsigned short h) {
    unsigned u = ((unsigned)h) << 16;
    return __builtin_bit_cast(float, u);
}

// async global->LDS, 16 bytes per lane (lane-contiguous dest)
__device__ __forceinline__ void gll16(const void* g, void* l) {
    __builtin_amdgcn_global_load_lds(
        (const __attribute__((address_space(1))) unsigned int*)g,
        (__attribute__((address_space(3))) unsigned int*)l,
        16, 0, 0);
}

// ---- prep: wswz = Wkv bf16, pre-permuted per 64-K tile so that a LINEAR
// global_load_lds produces the XOR-swizzled LDS layout the MFMA reads use.
// Also WqT bf16[272][128], WoT bf16[128][128].
#define WKV_N (256 * KPAD)          // 114688 shorts (7 tiles x 16384)
#define WQT_N (QDIM * ODIM)         // 34816
#define WOT_N (ODIM * ODIM)         // 16384
__global__ void prep_pack(const float* __restrict__ Wkv, const float* __restrict__ Wq,
                          const float* __restrict__ Wo,
                          unsigned short* __restrict__ wswz,
                          unsigned short* __restrict__ wqT,
                          unsigned short* __restrict__ woT) {
    int idx = blockIdx.x * 256 + threadIdx.x;
    if (idx < WKV_N) {
        int tile = idx >> 14;            // 16384 shorts per K-tile
        int qb   = (idx & 16383) * 2;    // byte offset within tile's LDS image
        int row  = qb >> 7;              // W row (128 B per row)
        int x    = qb & 127;
        int f8   = (x ^ ((row & 7) << 4)) >> 4;   // inverse of the read swizzle
        int e    = (x & 15) >> 1;
        int k    = tile * KSTEP + f8 * 8 + e;
        wswz[idx] = f2bf((k < KCAT) ? Wkv[row * KCAT + k] : 0.f);
    } else if (idx < WKV_N + WQT_N) {
        int j = idx - WKV_N;
        int k = j >> 7, c = j & 127;
        wqT[j] = f2bf(Wq[c * QDIM + k]);
    } else if (idx < WKV_N + WQT_N + WOT_N) {
        int j = idx - WKV_N - WQT_N;
        int k = j >> 7, c = j & 127;
        woT[j] = f2bf(Wo[c * ODIM + k]);
    }
}

// ---- Q projection: Q[B,128] = concat(node,time) @ Wq^T + bq  (coalesced via WqT)
__global__ __launch_bounds__(256) void q_proj(
    const float* __restrict__ node_feat, const float* __restrict__ time_feat,
    const unsigned short* __restrict__ wqT, const float* __restrict__ bq,
    float* __restrict__ Qbuf) {
    __shared__ float x[8][QDIM];
    const int tid = threadIdx.x;
    const long b0 = (long)blockIdx.x * 8;
    for (int g = tid; g < 8 * QDIM; g += 256) {
        int r = g / QDIM, k = g - r * QDIM;
        x[r][k] = (k < NDIM) ? node_feat[(b0 + r) * NDIM + k]
                             : time_feat[(b0 + r) * TDIM + (k - NDIM)];
    }
    __syncthreads();
    const int c = tid & 127;
    const int rb = (tid >> 7) * 4;
    float s0 = bq[c], s1 = s0, s2 = s0, s3 = s0;
    #pragma unroll 8
    for (int k = 0; k < QDIM; k++) {
        float w = bf2f(wqT[k * 128 + c]);
        s0 += x[rb + 0][k] * w;
        s1 += x[rb + 1][k] * w;
        s2 += x[rb + 2][k] * w;
        s3 += x[rb + 3][k] * w;
    }
    Qbuf[(b0 + rb + 0) * 128 + c] = s0;
    Qbuf[(b0 + rb + 1) * 128 + c] = s1;
    Qbuf[(b0 + rb + 2) * 128 + c] = s2;
    Qbuf[(b0 + rb + 3) * 128 + c] = s3;
}

__global__ __launch_bounds__(512, 4) void ta_fused(
    const float* __restrict__ edge_feat, const float* __restrict__ nbr_node,
    const float* __restrict__ nbr_time, const int* __restrict__ nbr_mask,
    const float* __restrict__ Qbuf,
    const unsigned short* __restrict__ wswz, const float* __restrict__ bkv,
    const unsigned short* __restrict__ woT, const float* __restrict__ bo,
    const float* __restrict__ gamma, const float* __restrict__ beta,
    float* __restrict__ out)
{
    // union: GEMM staging (A bf16 swz [64][64] @0 = 8K, W swz [256][64] @8K = 32K)
    // then Z bf16 [64][256] swizzled (32K)
    __shared__ __align__(16) unsigned char smem[40960];
    __shared__ float qres[BPB][ODIM];
    __shared__ float Pband[BPB][2][NNBR];
    __shared__ float Obuf[BPB][ODIM];
    __shared__ float red[4][2];

    const int tid  = threadIdx.x;
    const int lane = tid & 63;
    const int wid  = tid >> 6;
    const int b0   = blockIdx.x * BPB;

    // ---- stage precomputed Q rows (coalesced, 256 floats)
    if (tid < BPB * ODIM) {
        int b = tid >> 7, c = tid & 127;
        qres[b][c] = Qbuf[(long)(b0 + b) * ODIM + c];
    }

    // ---- GEMM: Z[64][256] = A[64][448] * Wkv[256][448]^T
    f32x4 acc[2][4];
    #pragma unroll
    for (int m = 0; m < 2; m++)
        #pragma unroll
        for (int n = 0; n < 4; n++) acc[m][n] = (f32x4){0.f, 0.f, 0.f, 0.f};

    const int wm = wid >> 2;   // 0..1 : 32-row band
    const int wn = wid & 3;    // 0..3 : 64-col band

    // per-thread constant staging geometry (hoisted out of the K loop)
    float4 areg[2];
    const float* pN[2]; const float* pE[2]; const float* pT[2];
    int a_koff[2], a_byte[2];
    #pragma unroll
    for (int i = 0; i < 2; i++) {
        int g = i * 512 + tid;            // [0,1024): 64 rows x 16 float4-groups
        int row = g >> 4, grp = g & 15;
        int bl = row >> 5, n = row & 31;
        long rg = (long)(b0 + bl) * NNBR + n;
        pN[i] = nbr_node  + rg * NDIM;
        pE[i] = edge_feat + rg * EDIM;
        pT[i] = nbr_time  + rg * TDIM;
        a_koff[i] = grp * 4;
        a_byte[i] = (row * 128 + grp * 8) ^ ((row & 7) << 4);
    }

    auto ISSUE_A = [&](int k0) {
        #pragma unroll
        for (int i = 0; i < 2; i++) {
            int k = k0 + a_koff[i];
            float4 v;
            if (k < NDIM)             v = *(const float4*)(pN[i] + k);
            else if (k < NDIM + EDIM) v = *(const float4*)(pE[i] + (k - NDIM));
            else if (k < KCAT)        v = *(const float4*)(pT[i] + (k - NDIM - EDIM));
            else                      v = make_float4(0.f, 0.f, 0.f, 0.f);
            areg[i] = v;
        }
    };

    ISSUE_A(0);

    for (int ks = 0; ks < NKS; ks++) {
        // W tile: pre-swizzled source, linear lane-contiguous async copy to LDS
        #pragma unroll
        for (int j = 0; j < 4; j++) {
            int s = j * 512 + tid;   // 16B chunk index [0,2048)
            gll16(wswz + (size_t)ks * 16384 + s * 8, smem + W_LDS_OFF + s * 16);
        }
        // A tile: staged regs -> bf16 -> swizzled LDS
        #pragma unroll
        for (int i = 0; i < 2; i++) {
            ushort4 h = make_ushort4(f2bf(areg[i].x), f2bf(areg[i].y),
                                     f2bf(areg[i].z), f2bf(areg[i].w));
            *(ushort4*)(smem + a_byte[i]) = h;
        }
        __syncthreads();                       // drains vmcnt (GLL) + lgkm
        if (ks < NKS - 1) ISSUE_A((ks + 1) * KSTEP);  // prefetch under compute
        // compute: two K=32 halves
        #pragma unroll
        for (int kk = 0; kk < 2; kk++) {
            const int kb = kk * 64 + (lane >> 4) * 16;
            bf16x8 af[2], bfr[4];
            #pragma unroll
            for (int m = 0; m < 2; m++) {
                int row = wm * 32 + m * 16 + (lane & 15);
                int byte = (row * 128 + kb) ^ ((row & 7) << 4);
                af[m] = __builtin_bit_cast(bf16x8, *(const short8*)(smem + byte));
            }
            #pragma unroll
            for (int n = 0; n < 4; n++) {
                int row = wn * 64 + n * 16 + (lane & 15);   // W row = Z column
                int byte = (row * 128 + kb) ^ ((row & 7) << 4);
                bfr[n] = __builtin_bit_cast(bf16x8, *(const short8*)(smem + W_LDS_OFF + byte));
            }
            #pragma unroll
            for (int m = 0; m < 2; m++)
                #pragma unroll
                for (int n = 0; n < 4; n++)
                    acc[m][n] = __builtin_amdgcn_mfma_f32_16x16x32_bf16(af[m], bfr[n], acc[m][n], 0, 0, 0);
        }
        __syncthreads();
    }

    // ---- dump Z (+bkv) to LDS as bf16 (swizzled); C/D: col=lane&15, row=(lane>>4)*4+j
    #pragma unroll
    for (int n = 0; n < 4; n++) {
        int col = wn * 64 + n * 16 + (lane & 15);
        float bk = bkv[col];
        #pragma unroll
        for (int m = 0; m < 2; m++) {
            #pragma unroll
            for (int j = 0; j < 4; j++) {
                int row = wm * 32 + m * 16 + (lane >> 4) * 4 + j;
                *(unsigned short*)(smem + ZB(row, col)) = f2bf(acc[m][n][j] + bk);
            }
        }
    }
    __syncthreads();

    // ---- scores + softmax: waves 0..3 -> (b=wid>>1, h=wid&1); lane pair per n2
    if (wid < 2 * BPB) {
        int bl = wid >> 1, h = wid & 1;
        int n2 = lane >> 1, half = lane & 1;
        int np = h * 16 + (n2 >> 1);                  // Z row (mixed reshape)
        int rowZ = bl * NNBR + np;
        int cb = (n2 & 1) * 64 + half * 32;           // Z col base (K part)
        const float* q = &qres[bl][h * 64 + half * 32];
        float s = 0.f;
        #pragma unroll
        for (int j = 0; j < 4; j++) {
            short8 z8 = *(const short8*)(smem + ZB(rowZ, cb + j * 8));
            #pragma unroll
            for (int e = 0; e < 8; e++)
                s += q[j * 8 + e] * bf2f((unsigned short)z8[e]);
        }
        s += __shfl_xor(s, 1);
        s *= 0.125f;  // HEAD_DIM^-0.5
        if (nbr_mask[(long)(b0 + bl) * NNBR + n2] == 0) s = -1e10f;
        float mx = s;
        #pragma unroll
        for (int off = 1; off < 64; off <<= 1) mx = fmaxf(mx, __shfl_xor(mx, off));
        float e = __expf(s - mx);
        float sum = e;
        #pragma unroll
        for (int off = 1; off < 64; off <<= 1) sum += __shfl_xor(sum, off);
        float p = e * 2.f / sum;   // each n2 counted twice in sum
        if (half == 0) Pband[bl][h][n2] = p;
    }
    __syncthreads();

    // ---- O = P @ V : one thread per (b, h*64+d)
    if (tid < BPB * ODIM) {
        int b = tid >> 7, c = tid & 127, h = c >> 6, d = c & 63;
        const float* P = Pband[b][h];
        float s = 0.f;
        #pragma unroll
        for (int n2 = 0; n2 < NNBR; n2++) {
            int np = h * 16 + (n2 >> 1);
            int col = ODIM + (n2 & 1) * 64 + d;       // V part
            s += P[n2] * bf2f(*(const unsigned short*)(smem + ZB(b * NNBR + np, col)));
        }
        Obuf[b][c] = s;
    }
    __syncthreads();

    // ---- out proj (coalesced via WoT) + LayerNorm
    {
        int b = tid >> 7, c = tid & 127;
        float s = 0.f;
        if (tid < BPB * ODIM) {
            s = bo[c];
            const float* ob = Obuf[b];
            #pragma unroll 8
            for (int k = 0; k < ODIM; k++)
                s += ob[k] * bf2f(woT[k * 128 + c]);
        }
        float s1 = s, s2 = s * s;
        #pragma unroll
        for (int off = 1; off < 64; off <<= 1) {
            s1 += __shfl_xor(s1, off);
            s2 += __shfl_xor(s2, off);
        }
        if (wid < 2 * BPB && lane == 0) { red[wid][0] = s1; red[wid][1] = s2; }
        __syncthreads();
        if (tid < BPB * ODIM) {
            float t1 = red[b * 2][0] + red[b * 2 + 1][0];
            float t2 = red[b * 2][1] + red[b * 2 + 1][1];
            float mu  = t1 * (1.f / 128.f);
            float var = t2 * (1.f / 128.f) - mu * mu;
            float inv = rsqrtf(var + LN_EPS);
            out[(long)(b0 + b) * ODIM + c] = (s - mu) * inv * gamma[c] + beta[c];
        }
    }
}

extern "C" void kernel_launch(void* const* d_in, const int* in_sizes, int n_in,
                              void* d_out, int out_size, void* d_ws, size_t ws_size,
                              hipStream_t stream) {
    const float* node_feat = (const float*)d_in[0];
    const float* time_feat = (const float*)d_in[1];
    const float* edge_feat = (const float*)d_in[2];
    const float* nbr_node  = (const float*)d_in[3];
    const float* nbr_time  = (const float*)d_in[4];
    const int*   nbr_mask  = (const int*)d_in[5];
    const float* Wq   = (const float*)d_in[6];
    const float* bq   = (const float*)d_in[7];
    const float* Wkv  = (const float*)d_in[8];
    const float* bkv  = (const float*)d_in[9];
    const float* Wo   = (const float*)d_in[10];
    const float* bo   = (const float*)d_in[11];
    const float* gma  = (const float*)d_in[12];
    const float* bta  = (const float*)d_in[13];
    float* out = (float*)d_out;

    const int B = in_sizes[0] / NDIM;  // 8192

    // workspace layout
    char* ws = (char*)d_ws;
    float* Qbuf = (float*)ws;                                   // B*128*4 = 4 MB
    unsigned short* wswz = (unsigned short*)(ws + (size_t)B * ODIM * 4);
    unsigned short* wqT  = wswz + WKV_N;
    unsigned short* woT  = wqT + WQT_N;

    const int prep_total = WKV_N + WQT_N + WOT_N;
    prep_pack<<<dim3((prep_total + 255) / 256), dim3(256), 0, stream>>>(
        Wkv, Wq, Wo, wswz, wqT, woT);
    q_proj<<<dim3(B / 8), dim3(256), 0, stream>>>(node_feat, time_feat, wqT, bq, Qbuf);
    ta_fused<<<dim3(B / BPB), dim3(512), 0, stream>>>(
        edge_feat, nbr_node, nbr_time, nbr_mask, Qbuf,
        wswz, bkv, woT, bo, gma, bta, out);
}